// Round 5
// baseline (212.780 us; speedup 1.0000x reference)
//
#include <hip/hip_runtime.h>
#include <hip/hip_bf16.h>

#define D 128
#define K 64

typedef __attribute__((ext_vector_type(8))) short short8;   // 8 bf16 in 4 VGPRs
typedef __attribute__((ext_vector_type(4))) float f32x4;

// round-to-nearest-even float -> bf16 bits (prep only)
__device__ inline short f2bf(float f) {
  union { float f; unsigned u; } v; v.f = f;
  unsigned u = v.u;
  return (short)((u + 0x7fffu + ((u >> 16) & 1u)) >> 16);
}

// packed f32x2 -> bf16x2 (v_cvt_pk_bf16_f32)
__device__ inline unsigned pk2(float a, float b) {
  union { __hip_bfloat162 h; unsigned u; } c;
  c.h = __float22bfloat162_rn(make_float2(a, b));
  return c.u;
}

// VALU-pipe 16-lane rotate-add (DPP row_ror:N). Avoids ds_bpermute (LDS pipe).
template<int CTRL>
__device__ inline float dpp_add(float v) {
  int r = __builtin_amdgcn_update_dpp(0, __float_as_int(v), CTRL, 0xf, 0xf, true);
  return v + __int_as_float(r);
}
__device__ inline float row16_allsum(float v) {
  v = dpp_add<0x121>(v);   // row_ror:1
  v = dpp_add<0x122>(v);   // row_ror:2
  v = dpp_add<0x124>(v);   // row_ror:4
  v = dpp_add<0x128>(v);   // row_ror:8
  return v;                // every lane in the 16-lane row has the full sum
}

// ws layout (floats): [0..16) accumulator; [16..80) mnorm[64]; [128..) bf16(2*m) as 8192 shorts
__global__ void prep_kernel(const float* __restrict__ m, float* ws) {
  const int j = blockIdx.x;     // 64 blocks x 64 threads
  const int t = threadIdx.x;
  float a0 = m[j * D + t * 2];
  float a1 = m[j * D + t * 2 + 1];
  short* mb = (short*)(ws + 128);
  mb[j * D + t * 2]     = f2bf(2.0f * a0);
  mb[j * D + t * 2 + 1] = f2bf(2.0f * a1);
  float s = a0 * a0 + a1 * a1;
  for (int off = 1; off < 64; off <<= 1) s += __shfl_xor(s, off, 64);
  if (t == 0) ws[16 + j] = s;
  if (j == 0 && t < 16) ws[t] = 0.0f;
}

// No LDS in the main loop: m fragments in registers (loaded once, L2-hot),
// reductions on the VALU pipe via DPP. Each wave = independent barrier-free
// stream; per-kk interleave keeps peak VGPR ~130.
__launch_bounds__(256)
__global__ void main_kernel(const float* __restrict__ x, float* ws) {
  const float* mnorm = ws + 16;
  const short* mb = (const short*)(ws + 128);
  const int tid  = threadIdx.x;
  const int lane = tid & 63;
  const int wv   = tid >> 6;
  const int lid  = lane & 15;   // A row / C-D col (j)
  const int quad = lane >> 4;   // A k-group; C/D row = quad*4+reg

  const int wave = blockIdx.x * 4 + wv;          // 3072 waves
  // 16384 tiles over 3072 waves: first 1024 waves take 6, rest take 5
  const int cnt  = 5 + (wave < 1024 ? 1 : 0);
  const int base = wave * 5 + (wave < 1024 ? wave : 1024);

  // Issue tile-0 x loads FIRST (longest latency), then fill B regs while they fly.
  f32x4 v[8];
  {
    const float* xb = x + (size_t)(base * 16 + lid) * D + quad * 8;
#pragma unroll
    for (int kk = 0; kk < 4; ++kk) {
      v[2 * kk]     = *(const f32x4*)(xb + kk * 32);
      v[2 * kk + 1] = *(const f32x4*)(xb + kk * 32 + 4);
    }
  }

  // B fragments: full m in registers (64 VGPRs), read once from L2-hot mb.
  short8 bfr[4][4];
  float mn[4];
#pragma unroll
  for (int jt = 0; jt < 4; ++jt) {
    mn[jt] = mnorm[jt * 16 + lid];
#pragma unroll
    for (int kk = 0; kk < 4; ++kk)
      bfr[jt][kk] = *(const short8*)(mb + (jt * 16 + lid) * D + kk * 32 + quad * 8);
  }

  float hacc = 0.f;

  for (int it = 0; it < cnt; ++it) {
    const bool more = (it + 1 < cnt);
    const float* xn = x + (size_t)((base + it + 1) * 16 + lid) * D + quad * 8;

    f32x4 acc[4];
#pragma unroll
    for (int jt = 0; jt < 4; ++jt) acc[jt] = (f32x4){0.f, 0.f, 0.f, 0.f};

    // Per-kk: convert (frees v[2kk..]), immediately issue next tile's loads
    // for that chunk, then 4 MFMAs. Keeps only one a-frag live -> low VGPR.
#pragma unroll
    for (int kk = 0; kk < 4; ++kk) {
      f32x4 v0 = v[2 * kk], v1 = v[2 * kk + 1];
      union { short8 s; unsigned u[4]; } av;
      av.u[0] = pk2(v0[0], v0[1]);
      av.u[1] = pk2(v0[2], v0[3]);
      av.u[2] = pk2(v1[0], v1[1]);
      av.u[3] = pk2(v1[2], v1[3]);
      if (more) {
        v[2 * kk]     = *(const f32x4*)(xn + kk * 32);
        v[2 * kk + 1] = *(const f32x4*)(xn + kk * 32 + 4);
      }
#pragma unroll
      for (int jt = 0; jt < 4; ++jt)
        acc[jt] = __builtin_amdgcn_mfma_f32_16x16x32_bf16(av.s, bfr[jt][kk], acc[jt], 0, 0, 0);
    }

    // Epilogue: s = 2x.m - ||m||^2, |s| < ~45 -> no max pass needed.
    // H = ln(S0) - S1/S0 with S0 = sum e^s, S1 = sum s e^s.
#pragma unroll
    for (int r = 0; r < 4; ++r) {
      float s0 = acc[0][r] - mn[0];
      float s1 = acc[1][r] - mn[1];
      float s2 = acc[2][r] - mn[2];
      float s3 = acc[3][r] - mn[3];
      float e0 = __expf(s0), e1 = __expf(s1), e2 = __expf(s2), e3 = __expf(s3);
      float S0 = (e0 + e1) + (e2 + e3);
      float S1 = fmaf(s0, e0, fmaf(s1, e1, fmaf(s2, e2, s3 * e3)));
      S0 = row16_allsum(S0);
      S1 = row16_allsum(S1);
      float H = __logf(S0) - S1 / S0;   // identical across the 16-lane row
      if (lid == 0) hacc += H;          // count each row once (owner: lid 0)
    }
  }

  // wave reduce -> block reduce -> one atomic per block (one-time cost)
  for (int off = 1; off < 64; off <<= 1) hacc += __shfl_xor(hacc, off, 64);
  __shared__ float red[4];
  if (lane == 0) red[wv] = hacc;
  __syncthreads();
  if (tid == 0) atomicAdd(ws, red[0] + red[1] + red[2] + red[3]);
}

__global__ void final_kernel(const float* __restrict__ m, const float* ws, float* out, int nRows) {
  __shared__ float mu[D];
  int lane = threadIdx.x;  // 64 threads
  for (int d = lane; d < D; d += 64) {
    float s = 0.f;
    for (int j = 0; j < K; ++j) s += m[j * D + d];
    mu[d] = s * (1.0f / K);
  }
  __syncthreads();
  const float* mr = m + lane * D;
  float dot = 0.f;
  for (int d = 0; d < D; ++d) dot += mu[d] * mr[d];
  float s = 2.f * dot - ws[16 + lane];  // shift-invariant: drop ||mu||^2
  float t = s - 20.f;                   // safe shift
  float e = __expf(t);
  float S0 = e, S1 = t * e;
  for (int off = 1; off < 64; off <<= 1) {
    S0 += __shfl_xor(S0, off, 64);
    S1 += __shfl_xor(S1, off, 64);
  }
  float inter = __logf(S0) - S1 / S0;
  if (lane == 0) {
    float intra = ws[0] / (float)nRows;
    out[0] = intra - inter;  // LAMB = 1
    out[1] = intra;
    out[2] = inter;
  }
}

extern "C" void kernel_launch(void* const* d_in, const int* in_sizes, int n_in,
                              void* d_out, int out_size, void* d_ws, size_t ws_size,
                              hipStream_t stream) {
  const float* x = (const float*)d_in[0];
  const float* m = (const float*)d_in[1];
  float* ws = (float*)d_ws;
  float* out = (float*)d_out;
  const int N = in_sizes[0] / D;        // 262144

  prep_kernel<<<64, 64, 0, stream>>>(m, ws);

  // 768 blocks = 3072 waves (3 blocks/CU at ~130 VGPR), balanced 5/6-tile split
  main_kernel<<<768, 256, 0, stream>>>(x, ws);

  final_kernel<<<1, 64, 0, stream>>>(m, ws, out, N);
}